// Round 6
// baseline (305.051 us; speedup 1.0000x reference)
//
#include <hip/hip_runtime.h>
#include <math.h>

#define N_NODES 50000
#define N_EDGES 800000
#define HID 128
#define CAP 64                        // max in-degree; Poisson(16) -> P(>64) ~ 1e-18
#define SCAT_BLOCKS (N_EDGES / 256)   // 3125 (exact)
#define QKV_BLOCKS  ((N_NODES + 31) / 32)   // 1563
#define AO_BLOCKS   (N_NODES / 16)    // 3125 (exact)

typedef _Float16 f16_t;
typedef f16_t f16x8 __attribute__((ext_vector_type(8)));
typedef f16_t f16x2 __attribute__((ext_vector_type(2)));
typedef float f32x4 __attribute__((ext_vector_type(4)));

__device__ __forceinline__ uint f2h_bits(float x) {
    union { f16_t h; ushort u; } c; c.h = (f16_t)x; return (uint)c.u;
}
__device__ __forceinline__ f16x2 as_h2(uint u) {
    union { uint u_; f16x2 h; } c; c.u_ = u; return c.h;
}
// load 8 f32, convert to f16x8 (one MFMA operand)
__device__ __forceinline__ f16x8 cvt8(const float* p) {
    float4 f0 = *(const float4*)p;
    float4 f1 = *(const float4*)(p + 4);
    f16x8 r;
    r[0] = (f16_t)f0.x; r[1] = (f16_t)f0.y; r[2] = (f16_t)f0.z; r[3] = (f16_t)f0.w;
    r[4] = (f16_t)f1.x; r[5] = (f16_t)f1.y; r[6] = (f16_t)f1.z; r[7] = (f16_t)f1.w;
    return r;
}

// ---------------------------------------------------------------------------
// One kernel, two independent jobs (co-scheduled for latency hiding):
//   blocks [0, SCAT_BLOCKS)      : edge scatter into per-node slot lists
//   blocks [SCAT_BLOCKS, +QKV)   : fused Q/K/V projection, MFMA 16x16x32 f16,
//                                  weights converted f32->f16 in-register.
// Pack layout (matches attn): col pair (c, c+8), c = 32w+16t+i (i=0..7):
//   p = 16w + 8t + i, qp[row*64+p] = [q_c | q_{c+8}]  (f16 halves, *0.25)
//   kv[row*64+p] = { [k_c|k_{c+8}], [v_c|v_{c+8}] }
// Pair halves live in lanes m and m+8 of the same quad -> __shfl_xor(.,8)
// builds full words; lanes mrow<8 store coalesced uint/uint2.
__global__ __launch_bounds__(256) void scatter_qkv(
    const float* __restrict__ h,
    const float* __restrict__ Wq, const float* __restrict__ Wk,
    const float* __restrict__ Wv,
    const float* __restrict__ bq, const float* __restrict__ bk,
    const float* __restrict__ bv,
    const int* __restrict__ rows, const int* __restrict__ cols,
    int* __restrict__ cnt, int* __restrict__ slots,
    uint* __restrict__ qp, uint2* __restrict__ kv)
{
    if (blockIdx.x < SCAT_BLOCKS) {
        const int e = blockIdx.x * 256 + threadIdx.x;   // < N_EDGES exactly
        int r = rows[e];
        int p = atomicAdd(&cnt[r], 1);
        if (p < CAP) slots[r * CAP + p] = cols[e];
        return;
    }

    const int lane = threadIdx.x & 63;
    const int wid  = threadIdx.x >> 6;
    const int mrow = lane & 15;
    const int quad = lane >> 4;
    const int rb   = (blockIdx.x - SCAT_BLOCKS) * 32;

    // A fragments: 2 row-strips x 4 k-chunks, f32 h -> f16 in-register
    f16x8 a[2][4];
#pragma unroll
    for (int s = 0; s < 2; ++s) {
        if (rb + s * 16 >= N_NODES) break;
        const float* src = h + (size_t)(rb + s * 16 + mrow) * HID + quad * 8;
#pragma unroll
        for (int kc = 0; kc < 4; ++kc) a[s][kc] = cvt8(src + kc * 32);
    }

    const int c0 = wid * 32 + mrow;      // tile-0 column
    const int c1 = c0 + 16;              // tile-1 column

    f16x8 bfr[2][4];
    f32x4 accq[2][2], acck[2][2], accv[2][2];

#define LOAD_B(W)                                                       \
    _Pragma("unroll")                                                   \
    for (int kc = 0; kc < 4; ++kc) {                                    \
        bfr[0][kc] = cvt8((W) + c0 * HID + kc * 32 + quad * 8);         \
        bfr[1][kc] = cvt8((W) + c1 * HID + kc * 32 + quad * 8);         \
    }
#define RUN_MFMA(dst)                                                   \
    _Pragma("unroll")                                                   \
    for (int s = 0; s < 2; ++s) {                                       \
        dst[s][0] = (f32x4){0.f, 0.f, 0.f, 0.f};                        \
        dst[s][1] = (f32x4){0.f, 0.f, 0.f, 0.f};                        \
        if (rb + s * 16 >= N_NODES) continue;                           \
        _Pragma("unroll")                                               \
        for (int kc = 0; kc < 4; ++kc) {                                \
            dst[s][0] = __builtin_amdgcn_mfma_f32_16x16x32_f16(         \
                a[s][kc], bfr[0][kc], dst[s][0], 0, 0, 0);              \
            dst[s][1] = __builtin_amdgcn_mfma_f32_16x16x32_f16(         \
                a[s][kc], bfr[1][kc], dst[s][1], 0, 0, 0);              \
        }                                                               \
    }

    LOAD_B(Wq); RUN_MFMA(accq);
    LOAD_B(Wk); RUN_MFMA(acck);
    LOAD_B(Wv); RUN_MFMA(accv);
#undef LOAD_B
#undef RUN_MFMA

    const float bq0 = bq[c0], bq1 = bq[c1];
    const float bk0 = bk[c0], bk1 = bk[c1];
    const float bv0 = bv[c0], bv1 = bv[c1];
    const bool  lo  = (mrow & 8) == 0;     // pair-low lanes store
    const int   i   = mrow & 7;

#pragma unroll
    for (int s = 0; s < 2; ++s) {
        if (rb + s * 16 >= N_NODES) break;
#pragma unroll
        for (int r = 0; r < 4; ++r) {
            const size_t orow = rb + s * 16 + quad * 4 + r;
            // Q (pre-scaled by 1/sqrt(d_head) = 0.25)
            uint q0 = f2h_bits((accq[s][0][r] + bq0) * 0.25f);
            uint q1 = f2h_bits((accq[s][1][r] + bq1) * 0.25f);
            uint q0p = __shfl_xor(q0, 8), q1p = __shfl_xor(q1, 8);
            // K / V
            uint k0 = f2h_bits(acck[s][0][r] + bk0);
            uint k1 = f2h_bits(acck[s][1][r] + bk1);
            uint v0 = f2h_bits(accv[s][0][r] + bv0);
            uint v1 = f2h_bits(accv[s][1][r] + bv1);
            uint k0p = __shfl_xor(k0, 8), k1p = __shfl_xor(k1, 8);
            uint v0p = __shfl_xor(v0, 8), v1p = __shfl_xor(v1, 8);
            if (lo) {
                const size_t base = orow * 64 + 16 * wid + i;
                qp[base]     = q0 | (q0p << 16);             // tile0 pair
                qp[base + 8] = q1 | (q1p << 16);             // tile1 pair
                kv[base]     = make_uint2(k0 | (k0p << 16), v0 | (v0p << 16));
                kv[base + 8] = make_uint2(k1 | (k1p << 16), v1 | (v1p << 16));
            }
        }
    }
}

// ---------------------------------------------------------------------------
// Fused attention + output projection. Block = 4 waves x 4 nodes = 16 rows.
// Attention: lane l owns col pair (ce, ce+8), ce = 16*(l>>3)+(l&7); both map
// to head l&7, so xor-{8,16,32} butterfly sums the 8 lanes of one head.
// Per edge: scalar slot read (readfirstlane -> saddr kv load), one
// v_dot2_f32_f16 for the partial score, plain exp-sum (scores ~ N(0,1),
// no overflow risk). O staged in LDS (f16, stride 304 B: 16B-aligned,
// 2-way-free banks), then 8 MFMAs against in-register-converted Wo.
__global__ __launch_bounds__(256) void attn_out(
    const uint* __restrict__ qp, const uint2* __restrict__ kv,
    const int* __restrict__ cnt, const int* __restrict__ slots,
    const float* __restrict__ Wo, const float* __restrict__ bo,
    float* __restrict__ out)
{
    const int lane = threadIdx.x & 63;
    const int wid  = threadIdx.x >> 6;
    const int mrow = lane & 15;
    const int quad = lane >> 4;
    const int rb16 = blockIdx.x * 16;

    __shared__ f16_t lds[16][152];       // 304 B row stride

    // Wo B-fragments (needed after the sync; loads fly during attention)
    const int c0 = wid * 32 + mrow, c1 = c0 + 16;
    f16x8 bw[2][4];
#pragma unroll
    for (int kc = 0; kc < 4; ++kc) {
        bw[0][kc] = cvt8(Wo + c0 * HID + kc * 32 + quad * 8);
        bw[1][kc] = cvt8(Wo + c1 * HID + kc * 32 + quad * 8);
    }

    const int ce = 16 * (lane >> 3) + (lane & 7);

    for (int t = 0; t < 4; ++t) {
        const int node = rb16 + wid * 4 + t;
        const int un   = __builtin_amdgcn_readfirstlane(node);
        int deg = cnt[un];
        if (deg > CAP) deg = CAP;
        deg = __builtin_amdgcn_readfirstlane(deg);
        const int* srow = slots + (size_t)un * CAP;

        const f16x2 qh = as_h2(qp[(size_t)node * 64 + lane]);

        float ls[8] = {0,0,0,0,0,0,0,0};
        float Oa[8] = {0,0,0,0,0,0,0,0};
        float Ob[8] = {0,0,0,0,0,0,0,0};

        for (int base = 0; base < deg; base += 8) {
            uint2 rr[8];
#pragma unroll
            for (int u = 0; u < 8; ++u) {
                int j  = base + u;
                int jj = (j < deg) ? j : 0;
                int cc = __builtin_amdgcn_readfirstlane(srow[jj]); // SGPR base
                rr[u] = (kv + ((size_t)cc << 6))[lane];            // saddr form
            }
#pragma unroll
            for (int u = 0; u < 8; ++u) {
                float p = __builtin_amdgcn_fdot2(as_h2(rr[u].x), qh, 0.f, false);
                p += __shfl_xor(p, 8);
                p += __shfl_xor(p, 16);
                p += __shfl_xor(p, 32);
                float ex = __expf(p);                 // max |p| ~ 8 << 88: safe
                ex = (base + u < deg) ? ex : 0.f;     // padding lanes -> 0
                f16x2 vh = as_h2(rr[u].y);
                ls[u] += ex;
                Oa[u] += ex * (float)vh[0];
                Ob[u] += ex * (float)vh[1];
            }
        }

        const float l  = ((ls[0]+ls[1]) + (ls[2]+ls[3])) + ((ls[4]+ls[5]) + (ls[6]+ls[7]));
        const float O0 = ((Oa[0]+Oa[1]) + (Oa[2]+Oa[3])) + ((Oa[4]+Oa[5]) + (Oa[6]+Oa[7]));
        const float O1 = ((Ob[0]+Ob[1]) + (Ob[2]+Ob[3])) + ((Ob[4]+Ob[5]) + (Ob[6]+Ob[7]));
        const float inv = (l > 0.f) ? 1.f / l : 0.f;  // deg-0 -> rows of bo

        const int lrow = wid * 4 + t;
        lds[lrow][ce]     = (f16_t)(O0 * inv);
        lds[lrow][ce + 8] = (f16_t)(O1 * inv);
    }

    __syncthreads();

    // Output projection: 16 rows x 32 cols per wave, MFMA 16x16x32 f16
    f32x4 acc0 = (f32x4){0.f, 0.f, 0.f, 0.f};
    f32x4 acc1 = (f32x4){0.f, 0.f, 0.f, 0.f};
#pragma unroll
    for (int kc = 0; kc < 4; ++kc) {
        f16x8 af = *(const f16x8*)&lds[mrow][kc * 32 + quad * 8];
        acc0 = __builtin_amdgcn_mfma_f32_16x16x32_f16(af, bw[0][kc], acc0, 0, 0, 0);
        acc1 = __builtin_amdgcn_mfma_f32_16x16x32_f16(af, bw[1][kc], acc1, 0, 0, 0);
    }
    const float b0 = bo[c0], b1 = bo[c1];
#pragma unroll
    for (int r = 0; r < 4; ++r) {
        const size_t orow = rb16 + quad * 4 + r;
        out[orow * HID + c0] = acc0[r] + b0;
        out[orow * HID + c1] = acc1[r] + b1;
    }
}

// ---------------------------------------------------------------------------
extern "C" void kernel_launch(void* const* d_in, const int* in_sizes, int n_in,
                              void* d_out, int out_size, void* d_ws, size_t ws_size,
                              hipStream_t stream)
{
    const float* h    = (const float*)d_in[0];
    const int*   rows = (const int*)  d_in[1];
    const int*   cols = (const int*)  d_in[2];
    const float* Wq   = (const float*)d_in[3];
    const float* bq   = (const float*)d_in[4];
    const float* Wk   = (const float*)d_in[5];
    const float* bk   = (const float*)d_in[6];
    const float* Wv   = (const float*)d_in[7];
    const float* bv   = (const float*)d_in[8];
    const float* Wo   = (const float*)d_in[9];
    const float* bo   = (const float*)d_in[10];
    float* out = (float*)d_out;

    char* ws = (char*)d_ws;
    uint*  qp    = (uint*)ws;   ws += (size_t)N_NODES * 64 * 4;   // 12.8 MB
    uint2* kv    = (uint2*)ws;  ws += (size_t)N_NODES * 64 * 8;   // 25.6 MB
    int*   cnt   = (int*)ws;    ws += (size_t)N_NODES * 4;        //  0.2 MB
    int*   slots = (int*)ws;    // N*CAP ints, 12.8 MB

    hipMemsetAsync(cnt, 0, N_NODES * sizeof(int), stream);

    dim3 blk(256);
    scatter_qkv<<<SCAT_BLOCKS + QKV_BLOCKS, blk, 0, stream>>>(
        h, Wq, Wk, Wv, bq, bk, bv, rows, cols, cnt, slots, qp, kv);

    attn_out<<<AO_BLOCKS, blk, 0, stream>>>(qp, kv, cnt, slots, Wo, bo, out);
}

// Round 7
// 256.106 us; speedup vs baseline: 1.1911x; 1.1911x over previous
//
#include <hip/hip_runtime.h>
#include <math.h>

#define N_NODES 50000
#define N_EDGES 800000
#define HID 128
#define CAP 64                           // max in-degree; Poisson(16) -> P(>64) ~ 1e-18
#define EPT 8                            // edges per scatter thread
#define SCAT_THREADS (N_EDGES / EPT)     // 100000 (exact)
#define SCAT_BLOCKS ((SCAT_THREADS + 255) / 256)  // 391
#define QKV_BLOCKS  ((N_NODES + 31) / 32)         // 1563
#define ATTN_BLOCKS ((N_NODES + 3) / 4)           // 12500
#define OUT_BLOCKS  ((N_NODES + 63) / 64)         // 782

typedef _Float16 f16_t;
typedef f16_t f16x8 __attribute__((ext_vector_type(8)));
typedef f16_t f16x2 __attribute__((ext_vector_type(2)));
typedef float f32x4 __attribute__((ext_vector_type(4)));

__device__ __forceinline__ ushort f2h_bits(float x) {
    union { f16_t h; ushort u; } c; c.h = (f16_t)x; return c.u;
}
__device__ __forceinline__ f16x2 as_h2(uint u) {
    union { uint u_; f16x2 h; } c; c.u_ = u; return c.h;
}
// load 8 f32, convert to f16x8 (one MFMA operand)
__device__ __forceinline__ f16x8 cvt8(const float* p) {
    float4 f0 = *(const float4*)p;
    float4 f1 = *(const float4*)(p + 4);
    f16x8 r;
    r[0] = (f16_t)f0.x; r[1] = (f16_t)f0.y; r[2] = (f16_t)f0.z; r[3] = (f16_t)f0.w;
    r[4] = (f16_t)f1.x; r[5] = (f16_t)f1.y; r[6] = (f16_t)f1.z; r[7] = (f16_t)f1.w;
    return r;
}

// ---------------------------------------------------------------------------
// Edge scatter. 8 edges/thread: int4 vector loads, 8 INDEPENDENT returning
// atomics in flight per thread (hides far-atomic latency 8x), counters padded
// to one per 64B line (kills same-line RMW serialization at the coherence
// point — round 6 showed the packed-counter version costs ~110 us).
__global__ __launch_bounds__(256) void scatter(
    const int* __restrict__ rows, const int* __restrict__ cols,
    int* __restrict__ cnt, ushort* __restrict__ slots)
{
    const int t = blockIdx.x * 256 + threadIdx.x;
    if (t >= SCAT_THREADS) return;
    const int4* r4 = (const int4*)rows + (size_t)t * 2;
    const int4* c4 = (const int4*)cols + (size_t)t * 2;
    int4 ra = r4[0], rb = r4[1];
    int4 ca = c4[0], cb = c4[1];
    const int r[8] = {ra.x, ra.y, ra.z, ra.w, rb.x, rb.y, rb.z, rb.w};
    const int c[8] = {ca.x, ca.y, ca.z, ca.w, cb.x, cb.y, cb.z, cb.w};
    int p[8];
#pragma unroll
    for (int u = 0; u < 8; ++u)
        p[u] = atomicAdd(&cnt[r[u] << 4], 1);    // 64B-padded counter
#pragma unroll
    for (int u = 0; u < 8; ++u)
        if (p[u] < CAP) slots[(size_t)r[u] * CAP + p[u]] = (ushort)c[u];
}

// ---------------------------------------------------------------------------
// Fused Q/K/V projection, MFMA 16x16x32 f16; weights cvt'd f32->f16 in-reg.
// Block = 4 waves x 32 rows; wave w owns cols [32w, 32w+32).
// Pack layout (matches attn): col pair (c, c+8), c = 32w+16t+i (i=0..7):
//   p = 16w+8t+i; qp[row*64+p] = [q_c | q_{c+8}] f16 halves (*0.25)
//   kv[row*64+p] = { [k_c|k_{c+8}], [v_c|v_{c+8}] }
// Pair halves live in lanes m, m+8 of a quad -> __shfl_xor(.,8) builds words;
// lanes mrow<8 store coalesced uint/uint2 (full 64B lines per row).
__global__ __launch_bounds__(256) void gemm_qkv(
    const float* __restrict__ h,
    const float* __restrict__ Wq, const float* __restrict__ Wk,
    const float* __restrict__ Wv,
    const float* __restrict__ bq, const float* __restrict__ bk,
    const float* __restrict__ bv,
    uint* __restrict__ qp, uint2* __restrict__ kv)
{
    const int lane = threadIdx.x & 63;
    const int wid  = threadIdx.x >> 6;
    const int mrow = lane & 15;
    const int quad = lane >> 4;
    const int rb   = blockIdx.x * 32;

    f16x8 a[2][4];
#pragma unroll
    for (int s = 0; s < 2; ++s) {
        if (rb + s * 16 >= N_NODES) break;
        const float* src = h + (size_t)(rb + s * 16 + mrow) * HID + quad * 8;
#pragma unroll
        for (int kc = 0; kc < 4; ++kc) a[s][kc] = cvt8(src + kc * 32);
    }

    const int c0 = wid * 32 + mrow;
    const int c1 = c0 + 16;

    f16x8 bfr[2][4];
    f32x4 accq[2][2], acck[2][2], accv[2][2];

#define LOAD_B(W)                                                       \
    _Pragma("unroll")                                                   \
    for (int kc = 0; kc < 4; ++kc) {                                    \
        bfr[0][kc] = cvt8((W) + c0 * HID + kc * 32 + quad * 8);         \
        bfr[1][kc] = cvt8((W) + c1 * HID + kc * 32 + quad * 8);         \
    }
#define RUN_MFMA(dst)                                                   \
    _Pragma("unroll")                                                   \
    for (int s = 0; s < 2; ++s) {                                       \
        dst[s][0] = (f32x4){0.f, 0.f, 0.f, 0.f};                        \
        dst[s][1] = (f32x4){0.f, 0.f, 0.f, 0.f};                        \
        if (rb + s * 16 >= N_NODES) continue;                           \
        _Pragma("unroll")                                               \
        for (int kc = 0; kc < 4; ++kc) {                                \
            dst[s][0] = __builtin_amdgcn_mfma_f32_16x16x32_f16(         \
                a[s][kc], bfr[0][kc], dst[s][0], 0, 0, 0);              \
            dst[s][1] = __builtin_amdgcn_mfma_f32_16x16x32_f16(         \
                a[s][kc], bfr[1][kc], dst[s][1], 0, 0, 0);              \
        }                                                               \
    }

    LOAD_B(Wq); RUN_MFMA(accq);
    LOAD_B(Wk); RUN_MFMA(acck);
    LOAD_B(Wv); RUN_MFMA(accv);
#undef LOAD_B
#undef RUN_MFMA

    const float bq0 = bq[c0], bq1 = bq[c1];
    const float bk0 = bk[c0], bk1 = bk[c1];
    const float bv0 = bv[c0], bv1 = bv[c1];
    const bool  lo  = (mrow & 8) == 0;
    const int   i   = mrow & 7;

#pragma unroll
    for (int s = 0; s < 2; ++s) {
        if (rb + s * 16 >= N_NODES) break;
#pragma unroll
        for (int r = 0; r < 4; ++r) {
            const size_t orow = rb + s * 16 + quad * 4 + r;
            uint q0 = f2h_bits((accq[s][0][r] + bq0) * 0.25f);
            uint q1 = f2h_bits((accq[s][1][r] + bq1) * 0.25f);
            uint k0 = f2h_bits(acck[s][0][r] + bk0);
            uint k1 = f2h_bits(acck[s][1][r] + bk1);
            uint v0 = f2h_bits(accv[s][0][r] + bv0);
            uint v1 = f2h_bits(accv[s][1][r] + bv1);
            uint q0p = __shfl_xor(q0, 8), q1p = __shfl_xor(q1, 8);
            uint k0p = __shfl_xor(k0, 8), k1p = __shfl_xor(k1, 8);
            uint v0p = __shfl_xor(v0, 8), v1p = __shfl_xor(v1, 8);
            if (lo) {
                const size_t base = orow * 64 + 16 * wid + i;
                qp[base]     = q0 | (q0p << 16);
                qp[base + 8] = q1 | (q1p << 16);
                kv[base]     = make_uint2(k0 | (k0p << 16), v0 | (v0p << 16));
                kv[base + 8] = make_uint2(k1 | (k1p << 16), v1 | (v1p << 16));
            }
        }
    }
}

// ---------------------------------------------------------------------------
// One wave per node (round-4 structure: best measured), f16 + v_dot2_f32_f16.
// Lane l owns col pair (ce, ce+8), ce = 32*(l>>4)+16*((l>>3)&1)+(l&7); both
// map to head l&7, so xor-{8,16,32} butterfly sums the 8 lanes of one head.
// No running max (scores ~ N(0,1); f32 exp-sum exact).
__device__ __forceinline__ void edge_acc(uint2 rr, f16x2 qh,
                                         float& l, float& Oa, float& Ob)
{
    float p = __builtin_amdgcn_fdot2(as_h2(rr.x), qh, 0.f, false);
    p += __shfl_xor(p, 8);
    p += __shfl_xor(p, 16);
    p += __shfl_xor(p, 32);
    float ex = __expf(p);
    f16x2 vh = as_h2(rr.y);
    l  += ex;
    Oa += ex * (float)vh[0];
    Ob += ex * (float)vh[1];
}

__global__ __launch_bounds__(256) void attn(
    const uint* __restrict__ qp, const uint2* __restrict__ kv,
    const int* __restrict__ cnt, const ushort* __restrict__ slots,
    ushort* __restrict__ ao)
{
    const int lane = threadIdx.x & 63;
    const int node = blockIdx.x * 4 + (threadIdx.x >> 6);
    if (node >= N_NODES) return;

    const f16x2 qh = as_h2(qp[(size_t)node * 64 + lane]);

    int deg = cnt[node << 4];                  // padded counter
    if (deg > CAP) deg = CAP;
    const int myslot = (lane < deg) ? (int)slots[(size_t)node * CAP + lane] : 0;

    float ls[4] = {0.f, 0.f, 0.f, 0.f};
    float Oa[4] = {0.f, 0.f, 0.f, 0.f};
    float Ob[4] = {0.f, 0.f, 0.f, 0.f};

    int j = 0;
    for (; j + 4 <= deg; j += 4) {
        int s0 = __shfl(myslot, j);
        int s1 = __shfl(myslot, j + 1);
        int s2 = __shfl(myslot, j + 2);
        int s3 = __shfl(myslot, j + 3);
        uint2 r0 = kv[(size_t)s0 * 64 + lane];
        uint2 r1 = kv[(size_t)s1 * 64 + lane];
        uint2 r2 = kv[(size_t)s2 * 64 + lane];
        uint2 r3 = kv[(size_t)s3 * 64 + lane];
        edge_acc(r0, qh, ls[0], Oa[0], Ob[0]);
        edge_acc(r1, qh, ls[1], Oa[1], Ob[1]);
        edge_acc(r2, qh, ls[2], Oa[2], Ob[2]);
        edge_acc(r3, qh, ls[3], Oa[3], Ob[3]);
    }
    for (; j < deg; ++j) {
        int s = __shfl(myslot, j);
        uint2 rr = kv[(size_t)s * 64 + lane];
        edge_acc(rr, qh, ls[0], Oa[0], Ob[0]);
    }

    const float l  = (ls[0] + ls[1]) + (ls[2] + ls[3]);
    const float O0 = (Oa[0] + Oa[1]) + (Oa[2] + Oa[3]);
    const float O1 = (Ob[0] + Ob[1]) + (Ob[2] + Ob[3]);
    const float inv = (l > 0.f) ? 1.f / l : 0.f;   // deg-0 -> 0 (bo added later)

    const int ce = 32 * (lane >> 4) + 16 * ((lane >> 3) & 1) + (lane & 7);
    ao[(size_t)node * HID + ce]     = f2h_bits(O0 * inv);
    ao[(size_t)node * HID + ce + 8] = f2h_bits(O1 * inv);
}

// ---------------------------------------------------------------------------
// Output projection: C = A(f16) @ Wo^T + bo, fp32 row-major; Wo cvt'd in-reg.
__global__ __launch_bounds__(256) void gemm_out(
    const ushort* __restrict__ A, const float* __restrict__ Wo,
    const float* __restrict__ bias, float* __restrict__ out)
{
    const int lane = threadIdx.x & 63;
    const int wid  = threadIdx.x >> 6;
    const int mrow = lane & 15;
    const int quad = lane >> 4;
    const int rb   = blockIdx.x * 64;

    const int c0 = wid * 32 + mrow;
    const int c1 = c0 + 16;

    f16x8 bfr[2][4];
#pragma unroll
    for (int kc = 0; kc < 4; ++kc) {
        bfr[0][kc] = cvt8(Wo + c0 * HID + kc * 32 + quad * 8);
        bfr[1][kc] = cvt8(Wo + c1 * HID + kc * 32 + quad * 8);
    }

    f32x4 acc[4][2];
#pragma unroll
    for (int s = 0; s < 4; ++s) {
        acc[s][0] = (f32x4){0.f, 0.f, 0.f, 0.f};
        acc[s][1] = (f32x4){0.f, 0.f, 0.f, 0.f};
    }

#pragma unroll
    for (int s = 0; s < 4; ++s) {
        if (rb + s * 16 >= N_NODES) break;
        const ushort* ap = A + (size_t)(rb + s * 16 + mrow) * HID + quad * 8;
        f16x8 a0 = *(const f16x8*)(ap);
        f16x8 a1 = *(const f16x8*)(ap + 32);
        f16x8 a2 = *(const f16x8*)(ap + 64);
        f16x8 a3 = *(const f16x8*)(ap + 96);
        acc[s][0] = __builtin_amdgcn_mfma_f32_16x16x32_f16(a0, bfr[0][0], acc[s][0], 0, 0, 0);
        acc[s][1] = __builtin_amdgcn_mfma_f32_16x16x32_f16(a0, bfr[1][0], acc[s][1], 0, 0, 0);
        acc[s][0] = __builtin_amdgcn_mfma_f32_16x16x32_f16(a1, bfr[0][1], acc[s][0], 0, 0, 0);
        acc[s][1] = __builtin_amdgcn_mfma_f32_16x16x32_f16(a1, bfr[1][1], acc[s][1], 0, 0, 0);
        acc[s][0] = __builtin_amdgcn_mfma_f32_16x16x32_f16(a2, bfr[0][2], acc[s][0], 0, 0, 0);
        acc[s][1] = __builtin_amdgcn_mfma_f32_16x16x32_f16(a2, bfr[1][2], acc[s][1], 0, 0, 0);
        acc[s][0] = __builtin_amdgcn_mfma_f32_16x16x32_f16(a3, bfr[0][3], acc[s][0], 0, 0, 0);
        acc[s][1] = __builtin_amdgcn_mfma_f32_16x16x32_f16(a3, bfr[1][3], acc[s][1], 0, 0, 0);
    }

#pragma unroll
    for (int t = 0; t < 2; ++t) {
        const int c = (t == 0) ? c0 : c1;
        const float bc = bias[c];
#pragma unroll
        for (int s = 0; s < 4; ++s) {
            if (rb + s * 16 >= N_NODES) break;
#pragma unroll
            for (int r = 0; r < 4; ++r) {
                const size_t orow = rb + s * 16 + quad * 4 + r;
                out[orow * HID + c] = acc[s][t][r] + bc;
            }
        }
    }
}

// ---------------------------------------------------------------------------
extern "C" void kernel_launch(void* const* d_in, const int* in_sizes, int n_in,
                              void* d_out, int out_size, void* d_ws, size_t ws_size,
                              hipStream_t stream)
{
    const float* h    = (const float*)d_in[0];
    const int*   rows = (const int*)  d_in[1];
    const int*   cols = (const int*)  d_in[2];
    const float* Wq   = (const float*)d_in[3];
    const float* bq   = (const float*)d_in[4];
    const float* Wk   = (const float*)d_in[5];
    const float* bk   = (const float*)d_in[6];
    const float* Wv   = (const float*)d_in[7];
    const float* bv   = (const float*)d_in[8];
    const float* Wo   = (const float*)d_in[9];
    const float* bo   = (const float*)d_in[10];
    float* out = (float*)d_out;

    char* ws = (char*)d_ws;
    uint*   qp    = (uint*)ws;    ws += (size_t)N_NODES * 64 * 4;   // 12.8 MB
    uint2*  kv    = (uint2*)ws;   ws += (size_t)N_NODES * 64 * 8;   // 25.6 MB
    ushort* ao    = (ushort*)ws;  ws += (size_t)N_NODES * HID * 2;  // 12.8 MB
    int*    cnt   = (int*)ws;     ws += (size_t)N_NODES * 64;       //  3.2 MB (padded)
    ushort* slots = (ushort*)ws;  // N*CAP ushorts, 6.4 MB

    hipMemsetAsync(cnt, 0, (size_t)N_NODES * 64, stream);

    dim3 blk(256);
    scatter<<<SCAT_BLOCKS, blk, 0, stream>>>(rows, cols, cnt, slots);
    gemm_qkv<<<QKV_BLOCKS, blk, 0, stream>>>(h, Wq, Wk, Wv, bq, bk, bv, qp, kv);
    attn<<<ATTN_BLOCKS, blk, 0, stream>>>(qp, kv, cnt, slots, ao);
    gemm_out<<<OUT_BLOCKS, blk, 0, stream>>>(ao, Wo, bo, out);
}

// Round 8
// 234.561 us; speedup vs baseline: 1.3005x; 1.0919x over previous
//
#include <hip/hip_runtime.h>
#include <math.h>

#define N_NODES 50000
#define N_EDGES 800000
#define HID 128
#define CAP 64                              // max in-degree; Poisson(16) -> P(>64) ~ 1e-18

// prep grid partition: [scatter | weight-cvt | h-cvt]
#define SCAT_TH   (N_EDGES / 8)             // 100000 threads, 8 edges each
#define SCAT_BLK  ((SCAT_TH + 255) / 256)   // 391
#define WCVT_BLK  64                        // 4 mats x 4096 float4 / 256
#define HCVT_BLK  (N_NODES * HID / 4 / 256) // 6250
#define PREP_BLK  (SCAT_BLK + WCVT_BLK + HCVT_BLK)

#define QKV_BX    ((N_NODES + 31) / 32)     // 1563
#define ATTN_BLK  ((N_NODES + 3) / 4)       // 12500
#define OUT_BLK   ((N_NODES + 63) / 64)     // 782

typedef _Float16 f16_t;
typedef f16_t f16x8 __attribute__((ext_vector_type(8)));
typedef f16_t f16x2 __attribute__((ext_vector_type(2)));
typedef float f32x4 __attribute__((ext_vector_type(4)));

__device__ __forceinline__ ushort f2h_bits(float x) {
    union { f16_t h; ushort u; } c; c.h = (f16_t)x; return c.u;
}
__device__ __forceinline__ f16x2 as_h2(uint u) {
    union { uint u_; f16x2 h; } c; c.u_ = u; return c.h;
}

// ---------------------------------------------------------------------------
// prep: one grid, three independent jobs co-scheduled.
//   blocks [0, SCAT_BLK)    : edge scatter — 8 edges/thread, int4 loads,
//                             8 independent returning atomics in flight,
//                             64B-padded counters (round-7: fixed the 110 us)
//   next WCVT_BLK           : Wq/Wk/Wv/Wo f32 -> f16
//   next HCVT_BLK           : h f32 -> f16 (BW-bound; hides scatter latency)
__global__ __launch_bounds__(256) void prep(
    const float* __restrict__ h,
    const float* __restrict__ Wq, const float* __restrict__ Wk,
    const float* __restrict__ Wv, const float* __restrict__ Wo,
    ushort* __restrict__ hf, ushort* __restrict__ wf,     // wf: 4 mats concat
    const int* __restrict__ rows, const int* __restrict__ cols,
    int* __restrict__ cnt, ushort* __restrict__ slots)
{
    const int b = blockIdx.x;
    const int tid = threadIdx.x;

    if (b < SCAT_BLK) {
        const int t = b * 256 + tid;
        if (t < SCAT_TH) {
            const int4* r4 = (const int4*)rows + (size_t)t * 2;
            const int4* c4 = (const int4*)cols + (size_t)t * 2;
            int4 ra = r4[0], rb2 = r4[1];
            int4 ca = c4[0], cb = c4[1];
            const int r[8] = {ra.x, ra.y, ra.z, ra.w, rb2.x, rb2.y, rb2.z, rb2.w};
            const int c[8] = {ca.x, ca.y, ca.z, ca.w, cb.x, cb.y, cb.z, cb.w};
            int p[8];
#pragma unroll
            for (int u = 0; u < 8; ++u)
                p[u] = atomicAdd(&cnt[r[u] << 4], 1);     // 64B-padded counter
#pragma unroll
            for (int u = 0; u < 8; ++u)
                if (p[u] < CAP) slots[(size_t)r[u] * CAP + p[u]] = (ushort)c[u];
        }
    } else if (b < SCAT_BLK + WCVT_BLK) {
        const int t = (b - SCAT_BLK) * 256 + tid;         // [0, 16384)
        const int m = t >> 12, i = t & 4095;
        const float* src = (m == 0) ? Wq : (m == 1) ? Wk : (m == 2) ? Wv : Wo;
        float4 f = ((const float4*)src)[i];
        ushort4 o;
        o.x = f2h_bits(f.x); o.y = f2h_bits(f.y);
        o.z = f2h_bits(f.z); o.w = f2h_bits(f.w);
        ((ushort4*)(wf + m * 16384))[i] = o;
    } else {
        const int t = (b - SCAT_BLK - WCVT_BLK) * 256 + tid;  // [0, 1.6M)
        float4 f = ((const float4*)h)[t];
        ushort4 o;
        o.x = f2h_bits(f.x); o.y = f2h_bits(f.y);
        o.z = f2h_bits(f.z); o.w = f2h_bits(f.w);
        ((ushort4*)hf)[t] = o;
    }
}

// ---------------------------------------------------------------------------
// QKV projection, MFMA 16x16x32 f16, FLAT PIPELINE (round-7 post-mortem:
// serial LOAD_B->MFMA chains left everything idle). One 16-col n-tile per
// wave, 32 rows; ALL 20 loads (8 A + 12 W, distinct regs) issue in one burst,
// then 24 independent MFMAs. grid (1563, 2): blockIdx.y = column half.
// Pack layout (matches attn): tile T = 4*by+wid, col c = 16T+i (i=0..7 pairs
// with c+8, both head i): p = 8T+i; qp[row*64+p] = [q_c|q_{c+8}] (*0.25);
// kv[row*64+p] = { [k_c|k_{c+8}], [v_c|v_{c+8}] }. Pair halves sit in lanes
// m, m+8 of a quad -> one shfl_xor(8) each; lanes i<8 store coalesced.
__global__ __launch_bounds__(256) void gemm_qkv(
    const ushort* __restrict__ hf, const ushort* __restrict__ wf,
    const float* __restrict__ bq, const float* __restrict__ bk,
    const float* __restrict__ bv,
    uint* __restrict__ qp, uint2* __restrict__ kv)
{
    const int lane = threadIdx.x & 63;
    const int wid  = threadIdx.x >> 6;
    const int mrow = lane & 15;
    const int quad = lane >> 4;
    const int rb   = blockIdx.x * 32;
    const int T    = blockIdx.y * 4 + wid;     // n-tile 0..7
    const int c    = T * 16 + mrow;

    // A fragments (2 strips x 4 k-chunks), row-clamped at N
    f16x8 a[2][4];
#pragma unroll
    for (int s = 0; s < 2; ++s) {
        int ar = rb + s * 16 + mrow;
        if (ar >= N_NODES) ar = N_NODES - 1;
        const ushort* ap = hf + (size_t)ar * HID + quad * 8;
#pragma unroll
        for (int kc = 0; kc < 4; ++kc) a[s][kc] = *(const f16x8*)(ap + kc * 32);
    }
    // W fragments: all three mats, distinct registers
    f16x8 bQ[4], bK[4], bV[4];
#pragma unroll
    for (int kc = 0; kc < 4; ++kc) {
        const int off = c * HID + kc * 32 + quad * 8;
        bQ[kc] = *(const f16x8*)(wf + off);
        bK[kc] = *(const f16x8*)(wf + 16384 + off);
        bV[kc] = *(const f16x8*)(wf + 32768 + off);
    }

    f32x4 aq[2], ak[2], av[2];
#pragma unroll
    for (int s = 0; s < 2; ++s) {
        aq[s] = (f32x4){0.f, 0.f, 0.f, 0.f};
        ak[s] = (f32x4){0.f, 0.f, 0.f, 0.f};
        av[s] = (f32x4){0.f, 0.f, 0.f, 0.f};
    }
#pragma unroll
    for (int s = 0; s < 2; ++s)
#pragma unroll
        for (int kc = 0; kc < 4; ++kc) {
            aq[s] = __builtin_amdgcn_mfma_f32_16x16x32_f16(a[s][kc], bQ[kc], aq[s], 0, 0, 0);
            ak[s] = __builtin_amdgcn_mfma_f32_16x16x32_f16(a[s][kc], bK[kc], ak[s], 0, 0, 0);
            av[s] = __builtin_amdgcn_mfma_f32_16x16x32_f16(a[s][kc], bV[kc], av[s], 0, 0, 0);
        }

    const float bqc = bq[c], bkc = bk[c], bvc = bv[c];
    const bool  lo  = (mrow & 8) == 0;
    const int   i   = mrow & 7;
#pragma unroll
    for (int s = 0; s < 2; ++s)
#pragma unroll
        for (int r = 0; r < 4; ++r) {
            const int orow = rb + s * 16 + quad * 4 + r;
            uint qv = f2h_bits((aq[s][r] + bqc) * 0.25f);  // q pre-scaled 1/sqrt(d)
            uint kb = f2h_bits(ak[s][r] + bkc);
            uint vb = f2h_bits(av[s][r] + bvc);
            uint qh = __shfl_xor((int)qv, 8);
            uint kh = __shfl_xor((int)kb, 8);
            uint vh = __shfl_xor((int)vb, 8);
            if (lo && orow < N_NODES) {
                const size_t base = (size_t)orow * 64 + 8 * T + i;
                qp[base] = qv | (qh << 16);
                kv[base] = make_uint2(kb | (kh << 16), vb | (vh << 16));
            }
        }
}

// ---------------------------------------------------------------------------
// One wave per node (best measured structure), f16 kv + v_dot2_f32_f16.
// Lane l owns col pair (ce, ce+8), ce = 16*(l>>3)+(l&7); both head l&7, so
// xor-{8,16,32} butterfly sums exactly the 8 lanes of one head.
// No running max (scores ~ N(0,1); f32 exp-sum exact).
__device__ __forceinline__ void edge_acc(uint2 rr, f16x2 qh,
                                         float& l, float& Oa, float& Ob)
{
    float p = __builtin_amdgcn_fdot2(as_h2(rr.x), qh, 0.f, false);
    p += __shfl_xor(p, 8);
    p += __shfl_xor(p, 16);
    p += __shfl_xor(p, 32);
    float ex = __expf(p);
    f16x2 vh = as_h2(rr.y);
    l  += ex;
    Oa += ex * (float)vh[0];
    Ob += ex * (float)vh[1];
}

__global__ __launch_bounds__(256) void attn(
    const uint* __restrict__ qp, const uint2* __restrict__ kv,
    const int* __restrict__ cnt, const ushort* __restrict__ slots,
    ushort* __restrict__ ao)
{
    const int lane = threadIdx.x & 63;
    const int node = blockIdx.x * 4 + (threadIdx.x >> 6);
    if (node >= N_NODES) return;

    const f16x2 qh = as_h2(qp[(size_t)node * 64 + lane]);

    int deg = cnt[node << 4];                  // padded counter
    if (deg > CAP) deg = CAP;
    const int myslot = (lane < deg) ? (int)slots[(size_t)node * CAP + lane] : 0;

    float ls[4] = {0.f, 0.f, 0.f, 0.f};
    float Oa[4] = {0.f, 0.f, 0.f, 0.f};
    float Ob[4] = {0.f, 0.f, 0.f, 0.f};

    int j = 0;
    for (; j + 4 <= deg; j += 4) {
        int s0 = __shfl(myslot, j);
        int s1 = __shfl(myslot, j + 1);
        int s2 = __shfl(myslot, j + 2);
        int s3 = __shfl(myslot, j + 3);
        uint2 r0 = kv[(size_t)s0 * 64 + lane];
        uint2 r1 = kv[(size_t)s1 * 64 + lane];
        uint2 r2 = kv[(size_t)s2 * 64 + lane];
        uint2 r3 = kv[(size_t)s3 * 64 + lane];
        edge_acc(r0, qh, ls[0], Oa[0], Ob[0]);
        edge_acc(r1, qh, ls[1], Oa[1], Ob[1]);
        edge_acc(r2, qh, ls[2], Oa[2], Ob[2]);
        edge_acc(r3, qh, ls[3], Oa[3], Ob[3]);
    }
    for (; j < deg; ++j) {
        int s = __shfl(myslot, j);
        uint2 rr = kv[(size_t)s * 64 + lane];
        edge_acc(rr, qh, ls[0], Oa[0], Ob[0]);
    }

    const float l  = (ls[0] + ls[1]) + (ls[2] + ls[3]);
    const float O0 = (Oa[0] + Oa[1]) + (Oa[2] + Oa[3]);
    const float O1 = (Ob[0] + Ob[1]) + (Ob[2] + Ob[3]);
    const float inv = (l > 0.f) ? 1.f / l : 0.f;   // deg-0 -> 0 (bo added later)

    const int ce = 16 * (lane >> 3) + (lane & 7);
    ao[(size_t)node * HID + ce]     = f2h_bits(O0 * inv);
    ao[(size_t)node * HID + ce + 8] = f2h_bits(O1 * inv);
}

// ---------------------------------------------------------------------------
// Output projection, flat pipeline: all 24 loads (16 A + 8 W f16) up front,
// then 32 MFMAs. 64-row blocks, wave owns 2 n-tiles (32 cols).
__global__ __launch_bounds__(256) void gemm_out(
    const ushort* __restrict__ A, const ushort* __restrict__ wfo,
    const float* __restrict__ bias, float* __restrict__ out)
{
    const int lane = threadIdx.x & 63;
    const int wid  = threadIdx.x >> 6;
    const int mrow = lane & 15;
    const int quad = lane >> 4;
    const int rb   = blockIdx.x * 64;

    const int c0 = wid * 32 + mrow;
    const int c1 = c0 + 16;

    f16x8 a[4][4];
#pragma unroll
    for (int s = 0; s < 4; ++s) {
        int ar = rb + s * 16 + mrow;
        if (ar >= N_NODES) ar = N_NODES - 1;
        const ushort* ap = A + (size_t)ar * HID + quad * 8;
#pragma unroll
        for (int kc = 0; kc < 4; ++kc) a[s][kc] = *(const f16x8*)(ap + kc * 32);
    }
    f16x8 b0[4], b1[4];
#pragma unroll
    for (int kc = 0; kc < 4; ++kc) {
        b0[kc] = *(const f16x8*)(wfo + c0 * HID + kc * 32 + quad * 8);
        b1[kc] = *(const f16x8*)(wfo + c1 * HID + kc * 32 + quad * 8);
    }

    f32x4 acc[4][2];
#pragma unroll
    for (int s = 0; s < 4; ++s) {
        acc[s][0] = (f32x4){0.f, 0.f, 0.f, 0.f};
        acc[s][1] = (f32x4){0.f, 0.f, 0.f, 0.f};
    }
#pragma unroll
    for (int s = 0; s < 4; ++s)
#pragma unroll
        for (int kc = 0; kc < 4; ++kc) {
            acc[s][0] = __builtin_amdgcn_mfma_f32_16x16x32_f16(a[s][kc], b0[kc], acc[s][0], 0, 0, 0);
            acc[s][1] = __builtin_amdgcn_mfma_f32_16x16x32_f16(a[s][kc], b1[kc], acc[s][1], 0, 0, 0);
        }

    const float bc0 = bias[c0], bc1 = bias[c1];
#pragma unroll
    for (int s = 0; s < 4; ++s)
#pragma unroll
        for (int r = 0; r < 4; ++r) {
            const int orow = rb + s * 16 + quad * 4 + r;
            if (orow < N_NODES) {
                out[(size_t)orow * HID + c0] = acc[s][0][r] + bc0;
                out[(size_t)orow * HID + c1] = acc[s][1][r] + bc1;
            }
        }
}

// ---------------------------------------------------------------------------
extern "C" void kernel_launch(void* const* d_in, const int* in_sizes, int n_in,
                              void* d_out, int out_size, void* d_ws, size_t ws_size,
                              hipStream_t stream)
{
    const float* h    = (const float*)d_in[0];
    const int*   rows = (const int*)  d_in[1];
    const int*   cols = (const int*)  d_in[2];
    const float* Wq   = (const float*)d_in[3];
    const float* bq   = (const float*)d_in[4];
    const float* Wk   = (const float*)d_in[5];
    const float* bk   = (const float*)d_in[6];
    const float* Wv   = (const float*)d_in[7];
    const float* bv   = (const float*)d_in[8];
    const float* Wo   = (const float*)d_in[9];
    const float* bo   = (const float*)d_in[10];
    float* out = (float*)d_out;

    char* ws = (char*)d_ws;
    uint*   qp    = (uint*)ws;    ws += (size_t)N_NODES * 64 * 4;   // 12.8 MB
    uint2*  kv    = (uint2*)ws;   ws += (size_t)N_NODES * 64 * 8;   // 25.6 MB
    ushort* hf    = (ushort*)ws;  ws += (size_t)N_NODES * HID * 2;  // 12.8 MB
    ushort* ao    = (ushort*)ws;  ws += (size_t)N_NODES * HID * 2;  // 12.8 MB
    ushort* wf    = (ushort*)ws;  ws += 4 * 16384 * 2;              // 128 KB
    int*    cnt   = (int*)ws;     ws += (size_t)N_NODES * 64;       // 3.2 MB padded
    ushort* slots = (ushort*)ws;  // N*CAP ushorts, 6.4 MB

    hipMemsetAsync(cnt, 0, (size_t)N_NODES * 64, stream);

    dim3 blk(256);
    prep<<<PREP_BLK, blk, 0, stream>>>(h, Wq, Wk, Wv, Wo, hf, wf,
                                       rows, cols, cnt, slots);
    gemm_qkv<<<dim3(QKV_BX, 2), blk, 0, stream>>>(hf, wf, bq, bk, bv, qp, kv);
    attn<<<ATTN_BLK, blk, 0, stream>>>(qp, kv, cnt, slots, ao);
    gemm_out<<<OUT_BLK, blk, 0, stream>>>(ao, wf + 3 * 16384, bo, out);
}